// Round 1
// baseline (450.860 us; speedup 1.0000x reference)
//
#include <hip/hip_runtime.h>
#include <hip/hip_bf16.h>
#include <math.h>

#define HIDDEN 128
#define HEADS 8
#define SCALE 0.25f

#define GEMM_ROWS 64
#define WT_STRIDE 132

// Y[n][j] = sum_i X[n][i] * W[j][i] + bias[j];  X:(N,128) W:(128,128) Y:(N,128)
__global__ __launch_bounds__(256) void gemm_xwt_kernel(
    const float* __restrict__ X, const float* __restrict__ W,
    const float* __restrict__ bias, float* __restrict__ Y, int N)
{
  __shared__ float Wt[128 * WT_STRIDE];       // Wt[i][j] = W[j][i], stride 132 (pad: conflict-free b128 reads)
  __shared__ float Xs[GEMM_ROWS * 128];
  const int t = threadIdx.x;
  const int row_base = blockIdx.x * GEMM_ROWS;

  // Stage W transposed. Column-wise global reads (lanes over i => coalesced 256B),
  // LDS writes land 8-way conflicted (acceptable: amortized over 128-iter main loop).
  {
    const int i = t & 127;
    const int j0 = (t >> 7) * 64;
    #pragma unroll 8
    for (int jj = 0; jj < 64; ++jj) {
      const int j = j0 + jj;
      Wt[i * WT_STRIDE + j] = W[j * 128 + i];
    }
  }
  // Stage X tile (coalesced float4, conflict-free LDS writes)
  for (int idx4 = t; idx4 < GEMM_ROWS * 32; idx4 += 256) {
    const int row = idx4 >> 5;
    const int i0 = (idx4 & 31) << 2;
    const int g = row_base + row;
    float4 xv = make_float4(0.f, 0.f, 0.f, 0.f);
    if (g < N) xv = *(const float4*)&X[(size_t)g * 128 + i0];
    *(float4*)&Xs[row * 128 + i0] = xv;
  }
  __syncthreads();

  const int c4 = (t & 31) << 2;   // this thread's 4 output cols
  const int r0 = t >> 5;          // row offset 0..7; owns rows r0+8*ch
  float acc[8][4];
  #pragma unroll
  for (int ch = 0; ch < 8; ++ch)
    acc[ch][0] = acc[ch][1] = acc[ch][2] = acc[ch][3] = 0.f;

  #pragma unroll 2
  for (int i = 0; i < 128; ++i) {
    const float4 w4 = *(const float4*)&Wt[i * WT_STRIDE + c4];
    #pragma unroll
    for (int ch = 0; ch < 8; ++ch) {
      const float xv = Xs[(r0 + 8 * ch) * 128 + i];
      acc[ch][0] = fmaf(xv, w4.x, acc[ch][0]);
      acc[ch][1] = fmaf(xv, w4.y, acc[ch][1]);
      acc[ch][2] = fmaf(xv, w4.z, acc[ch][2]);
      acc[ch][3] = fmaf(xv, w4.w, acc[ch][3]);
    }
  }

  const float4 b4 = *(const float4*)&bias[c4];
  #pragma unroll
  for (int ch = 0; ch < 8; ++ch) {
    const int g = row_base + r0 + 8 * ch;
    if (g < N) {
      float4 o;
      o.x = acc[ch][0] + b4.x;
      o.y = acc[ch][1] + b4.y;
      o.z = acc[ch][2] + b4.z;
      o.w = acc[ch][3] + b4.w;
      *(float4*)&Y[(size_t)g * 128 + c4] = o;
    }
  }
}

__global__ __launch_bounds__(256) void count_edges_kernel(
    const int* __restrict__ ei, int E, int* __restrict__ counts)
{
  const int e = blockIdx.x * 256 + threadIdx.x;
  if (e < E) atomicAdd(&counts[ei[E + e]], 1);
}

// Exclusive scan of counts -> offsets; single block of 1024 threads, chunked.
__global__ __launch_bounds__(1024) void scan_kernel(
    const int* __restrict__ counts, int* __restrict__ offsets, int n)
{
  __shared__ int buf[1024];
  __shared__ int carry_s;
  if (threadIdx.x == 0) carry_s = 0;
  __syncthreads();
  for (int base = 0; base < n; base += 1024) {
    const int idx = base + threadIdx.x;
    const int x = (idx < n) ? counts[idx] : 0;
    buf[threadIdx.x] = x;
    __syncthreads();
    int val = x;
    for (int off = 1; off < 1024; off <<= 1) {
      const int other = (threadIdx.x >= off) ? buf[threadIdx.x - off] : 0;
      __syncthreads();
      val += other;
      buf[threadIdx.x] = val;
      __syncthreads();
    }
    const int carry = carry_s;                  // val = inclusive scan of chunk
    if (idx < n) offsets[idx] = carry + val - x;
    __syncthreads();
    if (threadIdx.x == 1023) carry_s = carry + val;
    __syncthreads();
  }
}

__global__ __launch_bounds__(256) void scatter_kernel(
    const int* __restrict__ ei, int E, const int* __restrict__ offsets,
    int* __restrict__ cursor, int* __restrict__ csr_src)
{
  const int e = blockIdx.x * 256 + threadIdx.x;
  if (e < E) {
    const int d = ei[E + e];
    const int p = atomicAdd(&cursor[d], 1);
    csr_src[offsets[d] + p] = ei[e];
  }
}

// One wave (64 lanes) per destination node. lane l owns row elements 2l, 2l+1;
// head h = l>>3. Flash-style online softmax over this dst's edge list.
__global__ __launch_bounds__(256) void edge_attn_kernel(
    const float* __restrict__ q, const float* __restrict__ k,
    const float* __restrict__ v, const float* __restrict__ eb,
    const int* __restrict__ offsets, const int* __restrict__ counts,
    const int* __restrict__ csr_src, float* __restrict__ agg, int Ndst)
{
  const int wave = blockIdx.x * 4 + (threadIdx.x >> 6);
  if (wave >= Ndst) return;
  const int lane = threadIdx.x & 63;
  const int dst = wave;
  const int h = lane >> 3;

  const float2 qv = *(const float2*)&q[(size_t)dst * 128 + 2 * lane];
  const float bias = eb[h];
  const int ro = offsets[dst];
  const int cnt = counts[dst];

  float m = -3.0e38f, s = 0.f, a0 = 0.f, a1 = 0.f;
  for (int tE = 0; tE < cnt; ++tE) {
    const int src = csr_src[ro + tE];
    const float2 kv = *(const float2*)&k[(size_t)src * 128 + 2 * lane];
    float p = qv.x * kv.x + qv.y * kv.y;
    p += __shfl_xor(p, 1);
    p += __shfl_xor(p, 2);
    p += __shfl_xor(p, 4);          // all 8 lanes of the head group hold the dot
    const float score = p * SCALE + bias;
    const float mn = fmaxf(m, score);
    const float corr = __expf(m - mn);
    const float e = __expf(score - mn);
    const float2 vv = *(const float2*)&v[(size_t)src * 128 + 2 * lane];
    s = s * corr + e;
    a0 = a0 * corr + e * vv.x;
    a1 = a1 * corr + e * vv.y;
    m = mn;
  }
  const float rs = 1.0f / (s + 1e-8f);
  float2 o;
  o.x = a0 * rs;
  o.y = a1 * rs;
  *(float2*)&agg[(size_t)dst * 128 + 2 * lane] = o;
}

extern "C" void kernel_launch(void* const* d_in, const int* in_sizes, int n_in,
                              void* d_out, int out_size, void* d_ws, size_t ws_size,
                              hipStream_t stream) {
  const float* x_src = (const float*)d_in[0];
  const float* x_dst = (const float*)d_in[1];
  const int*   ei    = (const int*)d_in[2];
  const float* Wq = (const float*)d_in[3];
  const float* bq = (const float*)d_in[4];
  const float* Wk = (const float*)d_in[5];
  const float* bk = (const float*)d_in[6];
  const float* Wv = (const float*)d_in[7];
  const float* bv = (const float*)d_in[8];
  const float* Wo = (const float*)d_in[9];
  const float* bo = (const float*)d_in[10];
  const float* eb = (const float*)d_in[11];

  const int Nsrc = in_sizes[0] / HIDDEN;
  const int Ndst = in_sizes[1] / HIDDEN;
  const int E    = in_sizes[2] / 2;

  // workspace carve-up (~103 MB)
  char* w = (char*)d_ws;
  float* q    = (float*)w; w += (size_t)Ndst * HIDDEN * sizeof(float);
  float* kbuf = (float*)w; w += (size_t)Nsrc * HIDDEN * sizeof(float);
  float* vbuf = (float*)w; w += (size_t)Nsrc * HIDDEN * sizeof(float);
  float* agg  = (float*)w; w += (size_t)Ndst * HIDDEN * sizeof(float);
  int* counts  = (int*)w; w += (size_t)Ndst * sizeof(int);
  int* cursor  = (int*)w; w += (size_t)Ndst * sizeof(int);
  int* offsets = (int*)w; w += (size_t)Ndst * sizeof(int);
  int* csr_src = (int*)w; w += (size_t)E * sizeof(int);

  hipMemsetAsync(counts, 0, (size_t)Ndst * 2 * sizeof(int), stream); // counts + cursor

  dim3 blk(256);
  const int gb_dst = (Ndst + GEMM_ROWS - 1) / GEMM_ROWS;
  const int gb_src = (Nsrc + GEMM_ROWS - 1) / GEMM_ROWS;
  gemm_xwt_kernel<<<gb_dst, blk, 0, stream>>>(x_dst, Wq, bq, q, Ndst);
  gemm_xwt_kernel<<<gb_src, blk, 0, stream>>>(x_src, Wk, bk, kbuf, Nsrc);
  gemm_xwt_kernel<<<gb_src, blk, 0, stream>>>(x_src, Wv, bv, vbuf, Nsrc);

  const int eblocks = (E + 255) / 256;
  count_edges_kernel<<<eblocks, blk, 0, stream>>>(ei, E, counts);
  scan_kernel<<<1, 1024, 0, stream>>>(counts, offsets, Ndst);
  scatter_kernel<<<eblocks, blk, 0, stream>>>(ei, E, offsets, cursor, csr_src);

  const int ablocks = (Ndst + 3) / 4;
  edge_attn_kernel<<<ablocks, blk, 0, stream>>>(q, kbuf, vbuf, eb, offsets,
                                                counts, csr_src, agg, Ndst);

  gemm_xwt_kernel<<<gb_dst, blk, 0, stream>>>(agg, Wo, bo, (float*)d_out, Ndst);
}

// Round 2
// 289.378 us; speedup vs baseline: 1.5580x; 1.5580x over previous
//
#include <hip/hip_runtime.h>
#include <hip/hip_bf16.h>
#include <math.h>

#define HIDDEN 128
#define HEADS 8
#define SCALE 0.25f
#define GEMM_ROWS 128
#define GEMM_THREADS 512

// Transpose 4 weight matrices (128x128) into T: T[m][i][j] = Wm[j][i]
__global__ __launch_bounds__(256) void transpose_w_kernel(
    const float* __restrict__ W0, const float* __restrict__ W1,
    const float* __restrict__ W2, const float* __restrict__ W3,
    float* __restrict__ T)
{
  __shared__ float tile[32][33];
  const int m = blockIdx.x >> 4;
  const int tidx = blockIdx.x & 15;
  const int tr = (tidx >> 2) * 32;   // j-range base in W
  const int tc = (tidx & 3) * 32;    // i-range base in W
  const float* W = (m == 0) ? W0 : (m == 1) ? W1 : (m == 2) ? W2 : W3;
  float* Tm = T + m * 16384;
  const int lx = threadIdx.x & 31, ly = threadIdx.x >> 5;  // 32x8
  #pragma unroll
  for (int r = 0; r < 32; r += 8)
    tile[ly + r][lx] = W[(tr + ly + r) * 128 + tc + lx];
  __syncthreads();
  #pragma unroll
  for (int r = 0; r < 32; r += 8)
    Tm[(tc + ly + r) * 128 + tr + lx] = tile[lx][ly + r];
}

// Y[n][j] = sum_i X[n][i] * Wt[i][j] + bias[j]
// mode 0: Y row-major (N,128). mode 1/2: write into interleaved kv buffer:
//   kv[n*256 + 4*(j>>1) + (j&1) + (mode==2 ? 2 : 0)]
__global__ __launch_bounds__(GEMM_THREADS) void gemm_xwt_kernel(
    const float* __restrict__ X, const float* __restrict__ Wt_g,
    const float* __restrict__ bias, float* __restrict__ Y, int N, int mode)
{
  __shared__ float Wt[128 * 128];
  __shared__ float Xs[GEMM_ROWS * 128];
  const int t = threadIdx.x;
  const int row_base = blockIdx.x * GEMM_ROWS;

  // Stage Wt: straight 64KB copy, coalesced + conflict-free.
  for (int idx4 = t; idx4 < 128 * 32; idx4 += GEMM_THREADS)
    *(float4*)&Wt[idx4 * 4] = *(const float4*)&Wt_g[idx4 * 4];
  // Stage X tile
  for (int idx4 = t; idx4 < GEMM_ROWS * 32; idx4 += GEMM_THREADS) {
    const int row = idx4 >> 5;
    const int i0 = (idx4 & 31) << 2;
    const int g = row_base + row;
    float4 xv = make_float4(0.f, 0.f, 0.f, 0.f);
    if (g < N) xv = *(const float4*)&X[(size_t)g * 128 + i0];
    *(float4*)&Xs[row * 128 + i0] = xv;
  }
  __syncthreads();

  const int c4 = (t & 31) << 2;   // 4 output cols
  const int r0 = t >> 5;          // 0..15; owns rows r0+16*ch
  float acc[8][4];
  #pragma unroll
  for (int ch = 0; ch < 8; ++ch)
    acc[ch][0] = acc[ch][1] = acc[ch][2] = acc[ch][3] = 0.f;

  for (int i0 = 0; i0 < 128; i0 += 4) {
    float4 w[4];
    #pragma unroll
    for (int r = 0; r < 4; ++r)
      w[r] = *(const float4*)&Wt[(i0 + r) * 128 + c4];
    #pragma unroll
    for (int ch = 0; ch < 8; ++ch) {
      const float4 x4 = *(const float4*)&Xs[(r0 + 16 * ch) * 128 + i0];
      acc[ch][0] = fmaf(x4.x, w[0].x, acc[ch][0]);
      acc[ch][1] = fmaf(x4.x, w[0].y, acc[ch][1]);
      acc[ch][2] = fmaf(x4.x, w[0].z, acc[ch][2]);
      acc[ch][3] = fmaf(x4.x, w[0].w, acc[ch][3]);
      acc[ch][0] = fmaf(x4.y, w[1].x, acc[ch][0]);
      acc[ch][1] = fmaf(x4.y, w[1].y, acc[ch][1]);
      acc[ch][2] = fmaf(x4.y, w[1].z, acc[ch][2]);
      acc[ch][3] = fmaf(x4.y, w[1].w, acc[ch][3]);
      acc[ch][0] = fmaf(x4.z, w[2].x, acc[ch][0]);
      acc[ch][1] = fmaf(x4.z, w[2].y, acc[ch][1]);
      acc[ch][2] = fmaf(x4.z, w[2].z, acc[ch][2]);
      acc[ch][3] = fmaf(x4.z, w[2].w, acc[ch][3]);
      acc[ch][0] = fmaf(x4.w, w[3].x, acc[ch][0]);
      acc[ch][1] = fmaf(x4.w, w[3].y, acc[ch][1]);
      acc[ch][2] = fmaf(x4.w, w[3].z, acc[ch][2]);
      acc[ch][3] = fmaf(x4.w, w[3].w, acc[ch][3]);
    }
  }

  const float4 b4 = *(const float4*)&bias[c4];
  #pragma unroll
  for (int ch = 0; ch < 8; ++ch) {
    const int g = row_base + r0 + 16 * ch;
    if (g >= N) continue;
    float4 o;
    o.x = acc[ch][0] + b4.x;
    o.y = acc[ch][1] + b4.y;
    o.z = acc[ch][2] + b4.z;
    o.w = acc[ch][3] + b4.w;
    if (mode == 0) {
      *(float4*)&Y[(size_t)g * 128 + c4] = o;
    } else {
      const size_t base = (size_t)g * 256 + 2 * c4 + ((mode == 2) ? 2 : 0);
      *(float2*)&Y[base] = make_float2(o.x, o.y);
      *(float2*)&Y[base + 4] = make_float2(o.z, o.w);
    }
  }
}

__global__ __launch_bounds__(256) void count_edges_kernel(
    const int* __restrict__ ei, int E, int* __restrict__ counts)
{
  const int e = (blockIdx.x * 256 + threadIdx.x) * 4;
  if (e + 4 <= E) {
    const int4 d = *(const int4*)&ei[E + e];
    atomicAdd(&counts[d.x], 1);
    atomicAdd(&counts[d.y], 1);
    atomicAdd(&counts[d.z], 1);
    atomicAdd(&counts[d.w], 1);
  } else {
    for (int k = e; k < E; ++k) atomicAdd(&counts[ei[E + k]], 1);
  }
}

__global__ __launch_bounds__(256) void reduce_counts_kernel(
    const int* __restrict__ counts, int n, int* __restrict__ bsums)
{
  const int idx = blockIdx.x * 256 + threadIdx.x;
  int x = (idx < n) ? counts[idx] : 0;
  #pragma unroll
  for (int off = 1; off < 64; off <<= 1) x += __shfl_xor(x, off);
  __shared__ int ws[4];
  if ((threadIdx.x & 63) == 0) ws[threadIdx.x >> 6] = x;
  __syncthreads();
  if (threadIdx.x == 0) bsums[blockIdx.x] = ws[0] + ws[1] + ws[2] + ws[3];
}

// exclusive in-place scan of nb (<=256) block sums; single block of 256
__global__ __launch_bounds__(256) void scan_bsums_kernel(int* bsums, int nb)
{
  __shared__ int buf[256];
  const int t = threadIdx.x;
  const int x = (t < nb) ? bsums[t] : 0;
  buf[t] = x;
  __syncthreads();
  int val = x;
  #pragma unroll
  for (int off = 1; off < 256; off <<= 1) {
    const int other = (t >= off) ? buf[t - off] : 0;
    __syncthreads();
    val += other;
    buf[t] = val;
    __syncthreads();
  }
  if (t < nb) bsums[t] = val - x;
}

__global__ __launch_bounds__(256) void scan_counts_kernel(
    const int* __restrict__ counts, int n, const int* __restrict__ bsums,
    int* __restrict__ offsets)
{
  const int idx = blockIdx.x * 256 + threadIdx.x;
  const int lane = threadIdx.x & 63, wid = threadIdx.x >> 6;
  const int x = (idx < n) ? counts[idx] : 0;
  int v = x;
  #pragma unroll
  for (int off = 1; off < 64; off <<= 1) {
    const int t2 = __shfl_up(v, off);
    if (lane >= off) v += t2;
  }
  __shared__ int wsum[4];
  if (lane == 63) wsum[wid] = v;
  __syncthreads();
  int wbase = 0;
  for (int p = 0; p < wid; ++p) wbase += wsum[p];
  if (idx < n) offsets[idx] = bsums[blockIdx.x] + wbase + v - x;
}

__global__ __launch_bounds__(256) void scatter_kernel(
    const int* __restrict__ ei, int E, const int* __restrict__ offsets,
    int* __restrict__ cursor, int* __restrict__ csr_src)
{
  const int e = (blockIdx.x * 256 + threadIdx.x) * 4;
  if (e + 4 <= E) {
    const int4 s = *(const int4*)&ei[e];
    const int4 d = *(const int4*)&ei[E + e];
    int p;
    p = atomicAdd(&cursor[d.x], 1); csr_src[offsets[d.x] + p] = s.x;
    p = atomicAdd(&cursor[d.y], 1); csr_src[offsets[d.y] + p] = s.y;
    p = atomicAdd(&cursor[d.z], 1); csr_src[offsets[d.z] + p] = s.z;
    p = atomicAdd(&cursor[d.w], 1); csr_src[offsets[d.w] + p] = s.w;
  } else {
    for (int k = e; k < E; ++k) {
      const int d = ei[E + k];
      const int p = atomicAdd(&cursor[d], 1);
      csr_src[offsets[d] + p] = ei[k];
    }
  }
}

// One wave per destination. lane l owns elems 2l,2l+1 (head = l>>3).
// kv interleaved: kv[src*256 + 4l .. 4l+3] = {k[2l],k[2l+1],v[2l],v[2l+1]}
// No max-subtraction: |score| <= ~6 by construction (see derivation), exp safe.
__global__ __launch_bounds__(256) void edge_attn_kernel(
    const float* __restrict__ q, const float* __restrict__ kv,
    const float* __restrict__ eb, const int* __restrict__ offsets,
    const int* __restrict__ counts, const int* __restrict__ csr_src,
    float* __restrict__ agg, int Ndst)
{
  const int wave = blockIdx.x * 4 + (threadIdx.x >> 6);
  if (wave >= Ndst) return;
  const int lane = threadIdx.x & 63;
  const float2 qv = *(const float2*)&q[(size_t)wave * 128 + 2 * lane];
  const float bias = eb[lane >> 3];
  const int ro = offsets[wave];
  const int cnt = counts[wave];

  float s = 0.f, a0 = 0.f, a1 = 0.f;
  int tE = 0;
  for (; tE + 2 <= cnt; tE += 2) {
    const int s0 = csr_src[ro + tE];
    const int s1 = csr_src[ro + tE + 1];
    const float4 f0 = *(const float4*)&kv[(size_t)s0 * 256 + 4 * lane];
    const float4 f1 = *(const float4*)&kv[(size_t)s1 * 256 + 4 * lane];
    float p0 = fmaf(qv.x, f0.x, qv.y * f0.y);
    float p1 = fmaf(qv.x, f1.x, qv.y * f1.y);
    p0 += __shfl_xor(p0, 1); p1 += __shfl_xor(p1, 1);
    p0 += __shfl_xor(p0, 2); p1 += __shfl_xor(p1, 2);
    p0 += __shfl_xor(p0, 4); p1 += __shfl_xor(p1, 4);
    const float e0 = __expf(fmaf(p0, SCALE, bias));
    const float e1 = __expf(fmaf(p1, SCALE, bias));
    s += e0 + e1;
    a0 = fmaf(e0, f0.z, fmaf(e1, f1.z, a0));
    a1 = fmaf(e0, f0.w, fmaf(e1, f1.w, a1));
  }
  if (tE < cnt) {
    const int s0 = csr_src[ro + tE];
    const float4 f0 = *(const float4*)&kv[(size_t)s0 * 256 + 4 * lane];
    float p0 = fmaf(qv.x, f0.x, qv.y * f0.y);
    p0 += __shfl_xor(p0, 1);
    p0 += __shfl_xor(p0, 2);
    p0 += __shfl_xor(p0, 4);
    const float e0 = __expf(fmaf(p0, SCALE, bias));
    s += e0;
    a0 = fmaf(e0, f0.z, a0);
    a1 = fmaf(e0, f0.w, a1);
  }
  const float rs = 1.0f / (s + 1e-8f);
  *(float2*)&agg[(size_t)wave * 128 + 2 * lane] = make_float2(a0 * rs, a1 * rs);
}

extern "C" void kernel_launch(void* const* d_in, const int* in_sizes, int n_in,
                              void* d_out, int out_size, void* d_ws, size_t ws_size,
                              hipStream_t stream) {
  const float* x_src = (const float*)d_in[0];
  const float* x_dst = (const float*)d_in[1];
  const int*   ei    = (const int*)d_in[2];
  const float* Wq = (const float*)d_in[3];
  const float* bq = (const float*)d_in[4];
  const float* Wk = (const float*)d_in[5];
  const float* bk = (const float*)d_in[6];
  const float* Wv = (const float*)d_in[7];
  const float* bv = (const float*)d_in[8];
  const float* Wo = (const float*)d_in[9];
  const float* bo = (const float*)d_in[10];
  const float* eb = (const float*)d_in[11];

  const int Nsrc = in_sizes[0] / HIDDEN;
  const int Ndst = in_sizes[1] / HIDDEN;
  const int E    = in_sizes[2] / 2;

  char* w = (char*)d_ws;
  float* q    = (float*)w; w += (size_t)Ndst * HIDDEN * sizeof(float);
  float* kv   = (float*)w; w += (size_t)Nsrc * 2 * HIDDEN * sizeof(float);
  float* agg  = (float*)w; w += (size_t)Ndst * HIDDEN * sizeof(float);
  float* WtT  = (float*)w; w += (size_t)4 * 128 * 128 * sizeof(float);
  int* counts  = (int*)w; w += (size_t)Ndst * sizeof(int);
  int* cursor  = (int*)w; w += (size_t)Ndst * sizeof(int);
  int* offsets = (int*)w; w += (size_t)Ndst * sizeof(int);
  int* bsums   = (int*)w; w += 256 * sizeof(int);
  int* csr_src = (int*)w; w += (size_t)E * sizeof(int);

  hipMemsetAsync(counts, 0, (size_t)Ndst * 2 * sizeof(int), stream); // counts+cursor

  dim3 blk256(256);
  transpose_w_kernel<<<64, blk256, 0, stream>>>(Wq, Wk, Wv, Wo, WtT);

  const int gb_dst = (Ndst + GEMM_ROWS - 1) / GEMM_ROWS;
  const int gb_src = (Nsrc + GEMM_ROWS - 1) / GEMM_ROWS;
  gemm_xwt_kernel<<<gb_dst, GEMM_THREADS, 0, stream>>>(x_dst, WtT, bq, q, Ndst, 0);
  gemm_xwt_kernel<<<gb_src, GEMM_THREADS, 0, stream>>>(x_src, WtT + 16384, bk, kv, Nsrc, 1);
  gemm_xwt_kernel<<<gb_src, GEMM_THREADS, 0, stream>>>(x_src, WtT + 32768, bv, kv, Nsrc, 2);

  const int e4blocks = (E / 4 + 255) / 256;
  count_edges_kernel<<<e4blocks, blk256, 0, stream>>>(ei, E, counts);

  const int nb = (Ndst + 255) / 256;
  reduce_counts_kernel<<<nb, blk256, 0, stream>>>(counts, Ndst, bsums);
  scan_bsums_kernel<<<1, blk256, 0, stream>>>(bsums, nb);
  scan_counts_kernel<<<nb, blk256, 0, stream>>>(counts, Ndst, bsums, offsets);

  scatter_kernel<<<e4blocks, blk256, 0, stream>>>(ei, E, offsets, cursor, csr_src);

  const int ablocks = (Ndst + 3) / 4;
  edge_attn_kernel<<<ablocks, blk256, 0, stream>>>(q, kv, eb, offsets, counts,
                                                   csr_src, agg, Ndst);

  gemm_xwt_kernel<<<gb_dst, GEMM_THREADS, 0, stream>>>(agg, WtT + 49152, bo, (float*)d_out, Ndst, 0);
}

// Round 3
// 222.913 us; speedup vs baseline: 2.0226x; 1.2982x over previous
//
#include <hip/hip_runtime.h>
#include <math.h>

#define HIDDEN 128
#define SCALE 0.25f

typedef __attribute__((ext_vector_type(8))) short short8v;
typedef __attribute__((ext_vector_type(4))) float f32x4;

__device__ __forceinline__ unsigned short f2bf(float f) {
  const unsigned u = __float_as_uint(f);
  const unsigned r = u + 0x7fffu + ((u >> 16) & 1u);   // RNE
  return (unsigned short)(r >> 16);
}
__device__ __forceinline__ float bflo(unsigned u) { return __uint_as_float(u << 16); }
__device__ __forceinline__ float bfhi(unsigned u) { return __uint_as_float(u & 0xffff0000u); }

// Convert 4 weight matrices (128x128 f32, row-major) to bf16 (same layout).
__global__ __launch_bounds__(256) void convert_w_kernel(
    const float* __restrict__ W0, const float* __restrict__ W1,
    const float* __restrict__ W2, const float* __restrict__ W3,
    unsigned short* __restrict__ Wb)
{
  const int idx = (blockIdx.x * 256 + threadIdx.x) * 4;  // grid 64 -> [0,65536)
  const int m = idx >> 14, off = idx & 16383;
  const float* W = (m == 0) ? W0 : (m == 1) ? W1 : (m == 2) ? W2 : W3;
  const float4 v = *(const float4*)&W[off];
  ushort4 h;
  h.x = f2bf(v.x); h.y = f2bf(v.y); h.z = f2bf(v.z); h.w = f2bf(v.w);
  *(ushort4*)&Wb[idx] = h;
}

// Y[g][col] = sum_i X[g][i] * W[col][i] + bias[col], via mfma_f32_16x16x32_bf16.
// A-frag: lane holds X[l&15][(l>>4)*8+j]; B-frag: W[col=l&15][(l>>4)*8+j] (row-major W, no transpose).
// C/D: row=(l>>4)*4+r, col=l&15  [m89-verified].
// mode 0: f32 out (stride 128). 1: bf16 out (stride 128). 2/3: bf16 into kvb row
// [k(128) | v(128)] at stride 256, k half (2) or v half (3).
__global__ __launch_bounds__(256) void gemm_mfma_kernel(
    const void* __restrict__ Xin, int x_bf16,
    const unsigned short* __restrict__ Wb,
    const float* __restrict__ bias,
    void* __restrict__ Y, int N, int mode)
{
  __shared__ __align__(16) char XsB[64 * 256];    // 64 rows x 128 bf16, swizzled
  __shared__ __align__(16) char WsB[128 * 256];   // 128 rows x 128 bf16, swizzled
  const int t = threadIdx.x;
  const int row_base = blockIdx.x * 64;

  // Stage W: straight copy with XOR swizzle (byte ^= (row&7)<<4).
  for (int c = t; c < 4096; c += 256) {
    const int row = c >> 5;
    const int b8 = (c & 31) << 3;
    const uint2 val = *(const uint2*)((const char*)Wb + row * 256 + b8);
    *(uint2*)&WsB[row * 256 + (b8 ^ ((row & 7) << 4))] = val;
  }
  // Stage X tile (convert f32->bf16 unless already bf16), same swizzle.
  if (!x_bf16) {
    const float* Xf = (const float*)Xin;
    for (int c = t; c < 2048; c += 256) {
      const int row = c >> 5;
      const int fc = (c & 31) << 2;
      const int g = row_base + row;
      float4 xv = make_float4(0.f, 0.f, 0.f, 0.f);
      if (g < N) xv = *(const float4*)&Xf[(size_t)g * 128 + fc];
      ushort4 h;
      h.x = f2bf(xv.x); h.y = f2bf(xv.y); h.z = f2bf(xv.z); h.w = f2bf(xv.w);
      *(ushort4*)&XsB[row * 256 + ((fc << 1) ^ ((row & 7) << 4))] = h;
    }
  } else {
    const unsigned short* Xh = (const unsigned short*)Xin;
    for (int c = t; c < 2048; c += 256) {
      const int row = c >> 5;
      const int fc = (c & 31) << 2;
      const int g = row_base + row;
      ushort4 h = make_ushort4(0, 0, 0, 0);
      if (g < N) h = *(const ushort4*)&Xh[(size_t)g * 128 + fc];
      *(ushort4*)&XsB[row * 256 + ((fc << 1) ^ ((row & 7) << 4))] = h;
    }
  }
  __syncthreads();

  const int l = t & 63, w = t >> 6;
  const int r16 = l & 15, g16 = l >> 4;
  const int sw = (r16 & 7) << 4;
  f32x4 acc[8];
  #pragma unroll
  for (int n = 0; n < 8; ++n) acc[n] = (f32x4){0.f, 0.f, 0.f, 0.f};

  const char* ax = &XsB[(w * 16 + r16) * 256];
  #pragma unroll
  for (int kk = 0; kk < 4; ++kk) {
    const int kb = (kk * 64 + g16 * 16) ^ sw;
    const short8v a = *(const short8v*)(ax + kb);
    #pragma unroll
    for (int n = 0; n < 8; ++n) {
      const short8v b = *(const short8v*)&WsB[(n * 16 + r16) * 256 + kb];
      acc[n] = __builtin_amdgcn_mfma_f32_16x16x32_bf16(a, b, acc[n], 0, 0, 0);
    }
  }

  #pragma unroll
  for (int n = 0; n < 8; ++n) {
    const int col = n * 16 + r16;
    const float bv = bias[col];
    #pragma unroll
    for (int r = 0; r < 4; ++r) {
      const int g = row_base + w * 16 + g16 * 4 + r;
      if (g >= N) continue;
      const float o = acc[n][r] + bv;
      if (mode == 0) {
        ((float*)Y)[(size_t)g * 128 + col] = o;
      } else if (mode == 1) {
        ((unsigned short*)Y)[(size_t)g * 128 + col] = f2bf(o);
      } else {
        ((unsigned short*)Y)[(size_t)g * 256 + ((mode == 2) ? 0 : 128) + col] = f2bf(o);
      }
    }
  }
}

__global__ __launch_bounds__(256) void count_edges_kernel(
    const int* __restrict__ ei, int E, int* __restrict__ counts)
{
  const int e = (blockIdx.x * 256 + threadIdx.x) * 4;
  if (e + 4 <= E) {
    const int4 d = *(const int4*)&ei[E + e];
    atomicAdd(&counts[d.x], 1);
    atomicAdd(&counts[d.y], 1);
    atomicAdd(&counts[d.z], 1);
    atomicAdd(&counts[d.w], 1);
  } else {
    for (int k = e; k < E; ++k) atomicAdd(&counts[ei[E + k]], 1);
  }
}

__global__ __launch_bounds__(256) void reduce_counts_kernel(
    const int* __restrict__ counts, int n, int* __restrict__ bsums)
{
  const int idx = blockIdx.x * 256 + threadIdx.x;
  int x = (idx < n) ? counts[idx] : 0;
  #pragma unroll
  for (int off = 1; off < 64; off <<= 1) x += __shfl_xor(x, off);
  __shared__ int ws[4];
  if ((threadIdx.x & 63) == 0) ws[threadIdx.x >> 6] = x;
  __syncthreads();
  if (threadIdx.x == 0) bsums[blockIdx.x] = ws[0] + ws[1] + ws[2] + ws[3];
}

__global__ __launch_bounds__(256) void scan_bsums_kernel(int* bsums, int nb)
{
  __shared__ int buf[256];
  const int t = threadIdx.x;
  const int x = (t < nb) ? bsums[t] : 0;
  buf[t] = x;
  __syncthreads();
  int val = x;
  #pragma unroll
  for (int off = 1; off < 256; off <<= 1) {
    const int other = (t >= off) ? buf[t - off] : 0;
    __syncthreads();
    val += other;
    buf[t] = val;
    __syncthreads();
  }
  if (t < nb) bsums[t] = val - x;
}

__global__ __launch_bounds__(256) void scan_counts_kernel(
    const int* __restrict__ counts, int n, const int* __restrict__ bsums,
    int* __restrict__ offsets)
{
  const int idx = blockIdx.x * 256 + threadIdx.x;
  const int lane = threadIdx.x & 63, wid = threadIdx.x >> 6;
  const int x = (idx < n) ? counts[idx] : 0;
  int v = x;
  #pragma unroll
  for (int off = 1; off < 64; off <<= 1) {
    const int t2 = __shfl_up(v, off);
    if (lane >= off) v += t2;
  }
  __shared__ int wsum[4];
  if (lane == 63) wsum[wid] = v;
  __syncthreads();
  int wbase = 0;
  for (int p = 0; p < wid; ++p) wbase += wsum[p];
  if (idx < n) offsets[idx] = bsums[blockIdx.x] + wbase + v - x;
}

__global__ __launch_bounds__(256) void scatter_kernel(
    const int* __restrict__ ei, int E, const int* __restrict__ offsets,
    int* __restrict__ cursor, int* __restrict__ csr_src)
{
  const int e = (blockIdx.x * 256 + threadIdx.x) * 4;
  if (e + 4 <= E) {
    const int4 s = *(const int4*)&ei[e];
    const int4 d = *(const int4*)&ei[E + e];
    int p;
    p = atomicAdd(&cursor[d.x], 1); csr_src[offsets[d.x] + p] = s.x;
    p = atomicAdd(&cursor[d.y], 1); csr_src[offsets[d.y] + p] = s.y;
    p = atomicAdd(&cursor[d.z], 1); csr_src[offsets[d.z] + p] = s.z;
    p = atomicAdd(&cursor[d.w], 1); csr_src[offsets[d.w] + p] = s.w;
  } else {
    for (int k = e; k < E; ++k) {
      const int d = ei[E + k];
      const int p = atomicAdd(&cursor[d], 1);
      csr_src[offsets[d] + p] = ei[k];
    }
  }
}

// One wave per destination. lane l owns cols 2l,2l+1 (head = l>>3).
// kvb row: [k 128 bf16 | v 128 bf16], 512B. Per-edge: two 4B gathers per lane.
// No max-subtraction: scores bounded (~±5 sd), exp safe in f32.
__global__ __launch_bounds__(256) void edge_attn_kernel(
    const unsigned short* __restrict__ qb, const unsigned short* __restrict__ kvb,
    const float* __restrict__ eb, const int* __restrict__ offsets,
    const int* __restrict__ counts, const int* __restrict__ csr_src,
    unsigned short* __restrict__ agg, int Ndst)
{
  const int wave = blockIdx.x * 4 + (threadIdx.x >> 6);
  if (wave >= Ndst) return;
  const int lane = threadIdx.x & 63;
  const unsigned qp = *(const unsigned*)&qb[(size_t)wave * 128 + 2 * lane];
  const float qx = bflo(qp), qy = bfhi(qp);
  const float bias = eb[lane >> 3];
  const int ro = offsets[wave];
  const int cnt = counts[wave];
  const unsigned short* kvl = kvb + 2 * lane;

  float s = 0.f, a0 = 0.f, a1 = 0.f;
  int tE = 0;
  for (; tE + 4 <= cnt; tE += 4) {
    const int s0 = csr_src[ro + tE + 0];
    const int s1 = csr_src[ro + tE + 1];
    const int s2 = csr_src[ro + tE + 2];
    const int s3 = csr_src[ro + tE + 3];
    const unsigned k0 = *(const unsigned*)&kvl[(size_t)s0 * 256];
    const unsigned v0 = *(const unsigned*)&kvl[(size_t)s0 * 256 + 128];
    const unsigned k1 = *(const unsigned*)&kvl[(size_t)s1 * 256];
    const unsigned v1 = *(const unsigned*)&kvl[(size_t)s1 * 256 + 128];
    const unsigned k2 = *(const unsigned*)&kvl[(size_t)s2 * 256];
    const unsigned v2 = *(const unsigned*)&kvl[(size_t)s2 * 256 + 128];
    const unsigned k3 = *(const unsigned*)&kvl[(size_t)s3 * 256];
    const unsigned v3 = *(const unsigned*)&kvl[(size_t)s3 * 256 + 128];
    float p0 = fmaf(qx, bflo(k0), qy * bfhi(k0));
    float p1 = fmaf(qx, bflo(k1), qy * bfhi(k1));
    float p2 = fmaf(qx, bflo(k2), qy * bfhi(k2));
    float p3 = fmaf(qx, bflo(k3), qy * bfhi(k3));
    p0 += __shfl_xor(p0, 1); p1 += __shfl_xor(p1, 1);
    p2 += __shfl_xor(p2, 1); p3 += __shfl_xor(p3, 1);
    p0 += __shfl_xor(p0, 2); p1 += __shfl_xor(p1, 2);
    p2 += __shfl_xor(p2, 2); p3 += __shfl_xor(p3, 2);
    p0 += __shfl_xor(p0, 4); p1 += __shfl_xor(p1, 4);
    p2 += __shfl_xor(p2, 4); p3 += __shfl_xor(p3, 4);
    const float e0 = __expf(fmaf(p0, SCALE, bias));
    const float e1 = __expf(fmaf(p1, SCALE, bias));
    const float e2 = __expf(fmaf(p2, SCALE, bias));
    const float e3 = __expf(fmaf(p3, SCALE, bias));
    s += (e0 + e1) + (e2 + e3);
    a0 = fmaf(e0, bflo(v0), a0); a1 = fmaf(e0, bfhi(v0), a1);
    a0 = fmaf(e1, bflo(v1), a0); a1 = fmaf(e1, bfhi(v1), a1);
    a0 = fmaf(e2, bflo(v2), a0); a1 = fmaf(e2, bfhi(v2), a1);
    a0 = fmaf(e3, bflo(v3), a0); a1 = fmaf(e3, bfhi(v3), a1);
  }
  for (; tE < cnt; ++tE) {
    const int s0 = csr_src[ro + tE];
    const unsigned k0 = *(const unsigned*)&kvl[(size_t)s0 * 256];
    const unsigned v0 = *(const unsigned*)&kvl[(size_t)s0 * 256 + 128];
    float p0 = fmaf(qx, bflo(k0), qy * bfhi(k0));
    p0 += __shfl_xor(p0, 1); p0 += __shfl_xor(p0, 2); p0 += __shfl_xor(p0, 4);
    const float e0 = __expf(fmaf(p0, SCALE, bias));
    s += e0;
    a0 = fmaf(e0, bflo(v0), a0); a1 = fmaf(e0, bfhi(v0), a1);
  }
  const float rs = 1.0f / (s + 1e-8f);
  const unsigned out = (unsigned)f2bf(a0 * rs) | ((unsigned)f2bf(a1 * rs) << 16);
  *(unsigned*)&agg[(size_t)wave * 128 + 2 * lane] = out;
}

extern "C" void kernel_launch(void* const* d_in, const int* in_sizes, int n_in,
                              void* d_out, int out_size, void* d_ws, size_t ws_size,
                              hipStream_t stream) {
  const float* x_src = (const float*)d_in[0];
  const float* x_dst = (const float*)d_in[1];
  const int*   ei    = (const int*)d_in[2];
  const float* Wq = (const float*)d_in[3];
  const float* bq = (const float*)d_in[4];
  const float* Wk = (const float*)d_in[5];
  const float* bk = (const float*)d_in[6];
  const float* Wv = (const float*)d_in[7];
  const float* bv = (const float*)d_in[8];
  const float* Wo = (const float*)d_in[9];
  const float* bo = (const float*)d_in[10];
  const float* eb = (const float*)d_in[11];

  const int Nsrc = in_sizes[0] / HIDDEN;
  const int Ndst = in_sizes[1] / HIDDEN;
  const int E    = in_sizes[2] / 2;

  char* w = (char*)d_ws;
  unsigned short* qb   = (unsigned short*)w; w += (size_t)Ndst * 128 * 2;
  unsigned short* kvb  = (unsigned short*)w; w += (size_t)Nsrc * 256 * 2;
  unsigned short* aggb = (unsigned short*)w; w += (size_t)Ndst * 128 * 2;
  unsigned short* Wb   = (unsigned short*)w; w += (size_t)4 * 16384 * 2;
  int* counts  = (int*)w; w += (size_t)Ndst * sizeof(int);
  int* cursor  = (int*)w; w += (size_t)Ndst * sizeof(int);
  int* offsets = (int*)w; w += (size_t)Ndst * sizeof(int);
  int* bsums   = (int*)w; w += 256 * sizeof(int);
  int* csr_src = (int*)w; w += (size_t)E * sizeof(int);

  hipMemsetAsync(counts, 0, (size_t)Ndst * 2 * sizeof(int), stream);  // counts+cursor

  dim3 blk256(256);
  convert_w_kernel<<<64, blk256, 0, stream>>>(Wq, Wk, Wv, Wo, Wb);

  const int gb_dst = (Ndst + 63) / 64;
  const int gb_src = (Nsrc + 63) / 64;
  gemm_mfma_kernel<<<gb_dst, blk256, 0, stream>>>(x_dst, 0, Wb,         bq, qb,  Ndst, 1);
  gemm_mfma_kernel<<<gb_src, blk256, 0, stream>>>(x_src, 0, Wb + 16384, bk, kvb, Nsrc, 2);
  gemm_mfma_kernel<<<gb_src, blk256, 0, stream>>>(x_src, 0, Wb + 32768, bv, kvb, Nsrc, 3);

  const int e4blocks = (E / 4 + 255) / 256;
  count_edges_kernel<<<e4blocks, blk256, 0, stream>>>(ei, E, counts);

  const int nb = (Ndst + 255) / 256;
  reduce_counts_kernel<<<nb, blk256, 0, stream>>>(counts, Ndst, bsums);
  scan_bsums_kernel<<<1, blk256, 0, stream>>>(bsums, nb);
  scan_counts_kernel<<<nb, blk256, 0, stream>>>(counts, Ndst, bsums, offsets);

  scatter_kernel<<<e4blocks, blk256, 0, stream>>>(ei, E, offsets, cursor, csr_src);

  const int ablocks = (Ndst + 3) / 4;
  edge_attn_kernel<<<ablocks, blk256, 0, stream>>>(qb, kvb, eb, offsets, counts,
                                                   csr_src, aggb, Ndst);

  gemm_mfma_kernel<<<gb_dst, blk256, 0, stream>>>(aggb, 1, Wb + 49152, bo, d_out, Ndst, 0);
}

// Round 4
// 169.620 us; speedup vs baseline: 2.6581x; 1.3142x over previous
//
#include <hip/hip_runtime.h>
#include <math.h>

#define HIDDEN 128
#define SCALE 0.25f

typedef __attribute__((ext_vector_type(8))) short short8v;
typedef __attribute__((ext_vector_type(4))) float f32x4;

__device__ __forceinline__ unsigned short f2bf(float f) {
  const unsigned u = __float_as_uint(f);
  const unsigned r = u + 0x7fffu + ((u >> 16) & 1u);   // RNE
  return (unsigned short)(r >> 16);
}
__device__ __forceinline__ float bflo(unsigned u) { return __uint_as_float(u << 16); }
__device__ __forceinline__ float bfhi(unsigned u) { return __uint_as_float(u & 0xffff0000u); }

// Build fragment-ordered bf16 weights for mfma_f32_16x16x32_bf16 B-operand.
// chunk = m*2048 + (n*4+kk)*64 + l  ->  8 bf16 = W_m[n*16+(l&15)][kk*32+(l>>4)*8 + 0..7]
__global__ __launch_bounds__(256) void convert_w_kernel(
    const float* __restrict__ W0, const float* __restrict__ W1,
    const float* __restrict__ W2, const float* __restrict__ W3,
    unsigned short* __restrict__ Wfrag)
{
  const int chunk = blockIdx.x * 256 + threadIdx.x;   // grid 32 -> 8192 chunks
  const int m = chunk >> 11;
  const int rem = chunk & 2047;
  const int l = rem & 63;
  const int nkk = rem >> 6;
  const int n = nkk >> 2, kk = nkk & 3;
  const float* W = (m == 0) ? W0 : (m == 1) ? W1 : (m == 2) ? W2 : W3;
  const int row = n * 16 + (l & 15);
  const int k0 = kk * 32 + (l >> 4) * 8;
  const float4 v0 = *(const float4*)&W[row * 128 + k0];
  const float4 v1 = *(const float4*)&W[row * 128 + k0 + 4];
  uint4 o;
  o.x = (unsigned)f2bf(v0.x) | ((unsigned)f2bf(v0.y) << 16);
  o.y = (unsigned)f2bf(v0.z) | ((unsigned)f2bf(v0.w) << 16);
  o.z = (unsigned)f2bf(v1.x) | ((unsigned)f2bf(v1.y) << 16);
  o.w = (unsigned)f2bf(v1.z) | ((unsigned)f2bf(v1.w) << 16);
  *(uint4*)&Wfrag[(size_t)chunk * 8] = o;
}

// Y[g][col] = sum_i X[g][i]*W[col][i] + bias[col]. 64 rows/block, 4 waves.
// A from LDS (XOR-swizzled, conflict-free); B straight from global Wfrag (L2-hot,
// coalesced 1KB/wave). C/D: row=(l>>4)*4+r, col=l&15 [m89-verified, R3-passed].
// mode 0: f32 out stride 128. 1: bf16 out stride 128. 2/3: bf16 into kvb row
// [k(128)|v(128)] stride 256, k half (2) or v half (3).
__global__ __launch_bounds__(256) void gemm_mfma_kernel(
    const void* __restrict__ Xin, int x_bf16,
    const unsigned short* __restrict__ Wfrag,
    const float* __restrict__ bias,
    void* __restrict__ Y, int N, int mode)
{
  __shared__ __align__(16) char XsB[64 * 256];    // 64 rows x 128 bf16, swizzled
  const int t = threadIdx.x;
  const int row_base = blockIdx.x * 64;

  // Stage X: batched loads (8 outstanding), then convert + swizzled LDS writes.
  if (!x_bf16) {
    const float* Xf = (const float*)Xin;
    float4 xv[8];
    #pragma unroll
    for (int it = 0; it < 8; ++it) {
      const int c = t + it * 256;
      const int row = c >> 5, fc = (c & 31) << 2;
      const int g = row_base + row;
      xv[it] = make_float4(0.f, 0.f, 0.f, 0.f);
      if (g < N) xv[it] = *(const float4*)&Xf[(size_t)g * 128 + fc];
    }
    #pragma unroll
    for (int it = 0; it < 8; ++it) {
      const int c = t + it * 256;
      const int row = c >> 5, b8 = (c & 31) << 3;
      uint2 p;
      p.x = (unsigned)f2bf(xv[it].x) | ((unsigned)f2bf(xv[it].y) << 16);
      p.y = (unsigned)f2bf(xv[it].z) | ((unsigned)f2bf(xv[it].w) << 16);
      *(uint2*)&XsB[row * 256 + (b8 ^ ((row & 7) << 4))] = p;
    }
  } else {
    const unsigned short* Xh = (const unsigned short*)Xin;
    uint2 hv[8];
    #pragma unroll
    for (int it = 0; it < 8; ++it) {
      const int c = t + it * 256;
      const int row = c >> 5, fc = (c & 31) << 2;
      const int g = row_base + row;
      hv[it] = make_uint2(0, 0);
      if (g < N) hv[it] = *(const uint2*)&Xh[(size_t)g * 128 + fc];
    }
    #pragma unroll
    for (int it = 0; it < 8; ++it) {
      const int c = t + it * 256;
      const int row = c >> 5, b8 = (c & 31) << 3;
      *(uint2*)&XsB[row * 256 + (b8 ^ ((row & 7) << 4))] = hv[it];
    }
  }
  __syncthreads();

  const int l = t & 63, w = t >> 6;
  const int r16 = l & 15, g16 = l >> 4;
  const int sw = (r16 & 7) << 4;
  f32x4 acc[8];
  #pragma unroll
  for (int n = 0; n < 8; ++n) acc[n] = (f32x4){0.f, 0.f, 0.f, 0.f};

  const char* ax = &XsB[(w * 16 + r16) * 256];
  const short8v* wf = (const short8v*)Wfrag + l;
  #pragma unroll
  for (int kk = 0; kk < 4; ++kk) {
    const short8v a = *(const short8v*)(ax + ((kk * 64 + g16 * 16) ^ sw));
    #pragma unroll
    for (int n = 0; n < 8; ++n) {
      const short8v b = wf[(n * 4 + kk) * 64];
      acc[n] = __builtin_amdgcn_mfma_f32_16x16x32_bf16(a, b, acc[n], 0, 0, 0);
    }
  }

  #pragma unroll
  for (int n = 0; n < 8; ++n) {
    const int col = n * 16 + r16;
    const float bv = bias[col];
    #pragma unroll
    for (int r = 0; r < 4; ++r) {
      const int g = row_base + w * 16 + g16 * 4 + r;
      if (g >= N) continue;
      const float o = acc[n][r] + bv;
      if (mode == 0) {
        ((float*)Y)[(size_t)g * 128 + col] = o;
      } else if (mode == 1) {
        ((unsigned short*)Y)[(size_t)g * 128 + col] = f2bf(o);
      } else {
        ((unsigned short*)Y)[(size_t)g * 256 + ((mode == 2) ? 0 : 128) + col] = f2bf(o);
      }
    }
  }
}

__global__ __launch_bounds__(256) void count_edges_kernel(
    const int* __restrict__ ei, int E, int* __restrict__ counts)
{
  const int e = (blockIdx.x * 256 + threadIdx.x) * 4;
  if (e + 4 <= E) {
    const int4 d = *(const int4*)&ei[E + e];
    atomicAdd(&counts[d.x], 1);
    atomicAdd(&counts[d.y], 1);
    atomicAdd(&counts[d.z], 1);
    atomicAdd(&counts[d.w], 1);
  } else {
    for (int k = e; k < E; ++k) atomicAdd(&counts[ei[E + k]], 1);
  }
}

__global__ __launch_bounds__(256) void reduce_counts_kernel(
    const int* __restrict__ counts, int n, int* __restrict__ bsums)
{
  const int idx = blockIdx.x * 256 + threadIdx.x;
  int x = (idx < n) ? counts[idx] : 0;
  #pragma unroll
  for (int off = 1; off < 64; off <<= 1) x += __shfl_xor(x, off);
  __shared__ int ws[4];
  if ((threadIdx.x & 63) == 0) ws[threadIdx.x >> 6] = x;
  __syncthreads();
  if (threadIdx.x == 0) bsums[blockIdx.x] = ws[0] + ws[1] + ws[2] + ws[3];
}

__global__ __launch_bounds__(256) void scan_bsums_kernel(int* bsums, int nb)
{
  __shared__ int buf[256];
  const int t = threadIdx.x;
  const int x = (t < nb) ? bsums[t] : 0;
  buf[t] = x;
  __syncthreads();
  int val = x;
  #pragma unroll
  for (int off = 1; off < 256; off <<= 1) {
    const int other = (t >= off) ? buf[t - off] : 0;
    __syncthreads();
    val += other;
    buf[t] = val;
    __syncthreads();
  }
  if (t < nb) bsums[t] = val - x;
}

__global__ __launch_bounds__(256) void scan_counts_kernel(
    const int* __restrict__ counts, int n, const int* __restrict__ bsums,
    int* __restrict__ offsets)
{
  const int idx = blockIdx.x * 256 + threadIdx.x;
  const int lane = threadIdx.x & 63, wid = threadIdx.x >> 6;
  const int x = (idx < n) ? counts[idx] : 0;
  int v = x;
  #pragma unroll
  for (int off = 1; off < 64; off <<= 1) {
    const int t2 = __shfl_up(v, off);
    if (lane >= off) v += t2;
  }
  __shared__ int wsum[4];
  if (lane == 63) wsum[wid] = v;
  __syncthreads();
  int wbase = 0;
  for (int p = 0; p < wid; ++p) wbase += wsum[p];
  if (idx < n) offsets[idx] = bsums[blockIdx.x] + wbase + v - x;
}

__global__ __launch_bounds__(256) void scatter_kernel(
    const int* __restrict__ ei, int E, const int* __restrict__ offsets,
    int* __restrict__ cursor, int* __restrict__ csr_src)
{
  const int e = (blockIdx.x * 256 + threadIdx.x) * 4;
  if (e + 4 <= E) {
    const int4 s = *(const int4*)&ei[e];
    const int4 d = *(const int4*)&ei[E + e];
    int p;
    p = atomicAdd(&cursor[d.x], 1); csr_src[offsets[d.x] + p] = s.x;
    p = atomicAdd(&cursor[d.y], 1); csr_src[offsets[d.y] + p] = s.y;
    p = atomicAdd(&cursor[d.z], 1); csr_src[offsets[d.z] + p] = s.z;
    p = atomicAdd(&cursor[d.w], 1); csr_src[offsets[d.w] + p] = s.w;
  } else {
    for (int k = e; k < E; ++k) {
      const int d = ei[E + k];
      const int p = atomicAdd(&cursor[d], 1);
      csr_src[offsets[d] + p] = ei[k];
    }
  }
}

// One wave per destination. lane l owns cols 2l,2l+1 (head = l>>3).
// kvb row: [k 128 bf16 | v 128 bf16], 512B. No max-subtraction (scores bounded).
__global__ __launch_bounds__(256) void edge_attn_kernel(
    const unsigned short* __restrict__ qb, const unsigned short* __restrict__ kvb,
    const float* __restrict__ eb, const int* __restrict__ offsets,
    const int* __restrict__ counts, const int* __restrict__ csr_src,
    unsigned short* __restrict__ agg, int Ndst)
{
  const int wave = blockIdx.x * 4 + (threadIdx.x >> 6);
  if (wave >= Ndst) return;
  const int lane = threadIdx.x & 63;
  const unsigned qp = *(const unsigned*)&qb[(size_t)wave * 128 + 2 * lane];
  const float qx = bflo(qp), qy = bfhi(qp);
  const float bias = eb[lane >> 3];
  const int ro = offsets[wave];
  const int cnt = counts[wave];
  const unsigned short* kvl = kvb + 2 * lane;

  float s = 0.f, a0 = 0.f, a1 = 0.f;
  int tE = 0;
  for (; tE + 4 <= cnt; tE += 4) {
    const int s0 = csr_src[ro + tE + 0];
    const int s1 = csr_src[ro + tE + 1];
    const int s2 = csr_src[ro + tE + 2];
    const int s3 = csr_src[ro + tE + 3];
    const unsigned k0 = *(const unsigned*)&kvl[(size_t)s0 * 256];
    const unsigned v0 = *(const unsigned*)&kvl[(size_t)s0 * 256 + 128];
    const unsigned k1 = *(const unsigned*)&kvl[(size_t)s1 * 256];
    const unsigned v1 = *(const unsigned*)&kvl[(size_t)s1 * 256 + 128];
    const unsigned k2 = *(const unsigned*)&kvl[(size_t)s2 * 256];
    const unsigned v2 = *(const unsigned*)&kvl[(size_t)s2 * 256 + 128];
    const unsigned k3 = *(const unsigned*)&kvl[(size_t)s3 * 256];
    const unsigned v3 = *(const unsigned*)&kvl[(size_t)s3 * 256 + 128];
    float p0 = fmaf(qx, bflo(k0), qy * bfhi(k0));
    float p1 = fmaf(qx, bflo(k1), qy * bfhi(k1));
    float p2 = fmaf(qx, bflo(k2), qy * bfhi(k2));
    float p3 = fmaf(qx, bflo(k3), qy * bfhi(k3));
    p0 += __shfl_xor(p0, 1); p1 += __shfl_xor(p1, 1);
    p2 += __shfl_xor(p2, 1); p3 += __shfl_xor(p3, 1);
    p0 += __shfl_xor(p0, 2); p1 += __shfl_xor(p1, 2);
    p2 += __shfl_xor(p2, 2); p3 += __shfl_xor(p3, 2);
    p0 += __shfl_xor(p0, 4); p1 += __shfl_xor(p1, 4);
    p2 += __shfl_xor(p2, 4); p3 += __shfl_xor(p3, 4);
    const float e0 = __expf(fmaf(p0, SCALE, bias));
    const float e1 = __expf(fmaf(p1, SCALE, bias));
    const float e2 = __expf(fmaf(p2, SCALE, bias));
    const float e3 = __expf(fmaf(p3, SCALE, bias));
    s += (e0 + e1) + (e2 + e3);
    a0 = fmaf(e0, bflo(v0), a0); a1 = fmaf(e0, bfhi(v0), a1);
    a0 = fmaf(e1, bflo(v1), a0); a1 = fmaf(e1, bfhi(v1), a1);
    a0 = fmaf(e2, bflo(v2), a0); a1 = fmaf(e2, bfhi(v2), a1);
    a0 = fmaf(e3, bflo(v3), a0); a1 = fmaf(e3, bfhi(v3), a1);
  }
  for (; tE < cnt; ++tE) {
    const int s0 = csr_src[ro + tE];
    const unsigned k0 = *(const unsigned*)&kvl[(size_t)s0 * 256];
    const unsigned v0 = *(const unsigned*)&kvl[(size_t)s0 * 256 + 128];
    float p0 = fmaf(qx, bflo(k0), qy * bfhi(k0));
    p0 += __shfl_xor(p0, 1); p0 += __shfl_xor(p0, 2); p0 += __shfl_xor(p0, 4);
    const float e0 = __expf(fmaf(p0, SCALE, bias));
    s += e0;
    a0 = fmaf(e0, bflo(v0), a0); a1 = fmaf(e0, bfhi(v0), a1);
  }
  const float rs = 1.0f / (s + 1e-8f);
  const unsigned out = (unsigned)f2bf(a0 * rs) | ((unsigned)f2bf(a1 * rs) << 16);
  *(unsigned*)&agg[(size_t)wave * 128 + 2 * lane] = out;
}

extern "C" void kernel_launch(void* const* d_in, const int* in_sizes, int n_in,
                              void* d_out, int out_size, void* d_ws, size_t ws_size,
                              hipStream_t stream) {
  const float* x_src = (const float*)d_in[0];
  const float* x_dst = (const float*)d_in[1];
  const int*   ei    = (const int*)d_in[2];
  const float* Wq = (const float*)d_in[3];
  const float* bq = (const float*)d_in[4];
  const float* Wk = (const float*)d_in[5];
  const float* bk = (const float*)d_in[6];
  const float* Wv = (const float*)d_in[7];
  const float* bv = (const float*)d_in[8];
  const float* Wo = (const float*)d_in[9];
  const float* bo = (const float*)d_in[10];
  const float* eb = (const float*)d_in[11];

  const int Nsrc = in_sizes[0] / HIDDEN;
  const int Ndst = in_sizes[1] / HIDDEN;
  const int E    = in_sizes[2] / 2;

  char* w = (char*)d_ws;
  unsigned short* qb   = (unsigned short*)w; w += (size_t)Ndst * 128 * 2;
  unsigned short* kvb  = (unsigned short*)w; w += (size_t)Nsrc * 256 * 2;
  unsigned short* aggb = (unsigned short*)w; w += (size_t)Ndst * 128 * 2;
  unsigned short* Wb   = (unsigned short*)w; w += (size_t)4 * 16384 * 2;
  int* counts  = (int*)w; w += (size_t)Ndst * sizeof(int);
  int* cursor  = (int*)w; w += (size_t)Ndst * sizeof(int);
  int* offsets = (int*)w; w += (size_t)Ndst * sizeof(int);
  int* bsums   = (int*)w; w += 256 * sizeof(int);
  int* csr_src = (int*)w; w += (size_t)E * sizeof(int);

  hipMemsetAsync(counts, 0, (size_t)Ndst * 2 * sizeof(int), stream);  // counts+cursor

  dim3 blk256(256);
  convert_w_kernel<<<32, blk256, 0, stream>>>(Wq, Wk, Wv, Wo, Wb);

  const int gb_dst = (Ndst + 63) / 64;
  const int gb_src = (Nsrc + 63) / 64;
  gemm_mfma_kernel<<<gb_dst, blk256, 0, stream>>>(x_dst, 0, Wb,         bq, qb,  Ndst, 1);
  gemm_mfma_kernel<<<gb_src, blk256, 0, stream>>>(x_src, 0, Wb + 16384, bk, kvb, Nsrc, 2);
  gemm_mfma_kernel<<<gb_src, blk256, 0, stream>>>(x_src, 0, Wb + 32768, bv, kvb, Nsrc, 3);

  const int e4blocks = (E / 4 + 255) / 256;
  count_edges_kernel<<<e4blocks, blk256, 0, stream>>>(ei, E, counts);

  const int nb = (Ndst + 255) / 256;
  reduce_counts_kernel<<<nb, blk256, 0, stream>>>(counts, Ndst, bsums);
  scan_bsums_kernel<<<1, blk256, 0, stream>>>(bsums, nb);
  scan_counts_kernel<<<nb, blk256, 0, stream>>>(counts, Ndst, bsums, offsets);

  scatter_kernel<<<e4blocks, blk256, 0, stream>>>(ei, E, offsets, cursor, csr_src);

  const int ablocks = (Ndst + 3) / 4;
  edge_attn_kernel<<<ablocks, blk256, 0, stream>>>(qb, kvb, eb, offsets, counts,
                                                   csr_src, aggb, Ndst);

  gemm_mfma_kernel<<<gb_dst, blk256, 0, stream>>>(aggb, 1, Wb + 49152, bo, d_out, Ndst, 0);
}